// Round 5
// baseline (523.082 us; speedup 1.0000x reference)
//
#include <hip/hip_runtime.h>

#define NUM_LEARNERS 50000
#define NUM_SCENES   2000
#define EMBED_DIM    128
#define HID          16

// Single fused kernel, one wave per learner row. Barrier-free.
//
// Algebra: sum_{j in nz} mlp[j] = W2^T (sum_{j in nz} h(j)) + count*b2, with
// h(j)[k] = relu(j*W1[k]+b1[k]) computed inline.
//
// R5 changes vs R4:
//  - NO __syncthreads: idxbuf row is wave-private; same-wave LDS RAW only
//    needs the compiler's lgkmcnt. Removes the vmcnt(0) barrier drain and
//    the 4-wave coupling.
//  - Ring-pipelined scan (depth 4): chunk it processed while it+1..it+4 in
//    flight (fine-grained vmcnt instead of drain-to-0); lower VGPR.
//  - Phase 2 split into unmasked full iterations + one masked tail.
//  - W1/b1 lane slices loaded as one dwordx4 each, just before phase 2.
__global__ __launch_bounds__(256) void fused_gather_mean_kernel(
    const float* __restrict__ M,
    const float* __restrict__ W1, const float* __restrict__ b1,
    const float* __restrict__ W2, const float* __restrict__ b2,
    float* __restrict__ out)
{
    // 2048-entry rows: phase-2 b64 reads stay in-bounds even at count=2000.
    __shared__ unsigned short idxbuf[4][2048];         // 16384 B
    const int  wave = threadIdx.x >> 6;
    const int  lane = threadIdx.x & 63;
    const long row  = (long)blockIdx.x * 4 + wave;

    const int g   = lane >> 2;   // phase-2 index group
    const int sub = lane & 3;    // phase-2 h-dim quad

    const float4* __restrict__ M4 = (const float4*)(M + row * NUM_SCENES); // 8000B row
    unsigned short* myidx = idxbuf[wave];

    // ---- Phase 0/1 fused: ring-pipelined scan + ballot compaction ----
    float4 ring[4];
#pragma unroll
    for (int it = 0; it < 4; ++it) {
        int c4 = it * 64 + lane;                 // < 256, always valid
        ring[it] = M4[c4];
    }

    int count = 0;
#pragma unroll
    for (int it = 0; it < 8; ++it) {
        float4 cur = ring[it & 3];
        if (it < 4) {                            // prefetch chunk it+4
            int c4 = (it + 4) * 64 + lane;
            if (c4 < 500) ring[it & 3] = M4[c4];
            else          ring[it & 3] = make_float4(0.f, 0.f, 0.f, 0.f);
        }
        int c4 = it * 64 + lane;
        float vals[4] = {cur.x, cur.y, cur.z, cur.w};
#pragma unroll
        for (int c = 0; c < 4; ++c) {
            bool nz = (vals[c] != 0.0f);
            unsigned long long m = __ballot(nz);
            if (nz) {
                int below = __builtin_amdgcn_mbcnt_hi(
                    (unsigned)(m >> 32),
                    __builtin_amdgcn_mbcnt_lo((unsigned)m, 0));
                myidx[count + below] = (unsigned short)(c4 * 4 + c);
            }
            count += __popcll(m);                // wave-uniform running total
        }
    }
    // No barrier: idxbuf[wave] is private to this wave; compiler inserts
    // lgkmcnt before the dependent ds_reads below.

    // Per-lane W1/b1 slice for dims 4*sub..4*sub+3 (one dwordx4 each, L1-hot).
    float4 w1v = ((const float4*)W1)[sub];
    float4 b1v = ((const float4*)b1)[sub];

    // ---- Phase 2: in-register h-sum, 64 indices per iteration ----
    float4 acc = make_float4(0.f, 0.f, 0.f, 0.f);
    const int nFull = count >> 6;
    for (int t = 0; t < nFull; ++t) {            // unmasked full iterations
        int base = t * 64 + g * 4;
        ushort4 idx4 = *(const ushort4*)&myidx[base];   // b64, bcast in group
        const unsigned short* iq = (const unsigned short*)&idx4;
#pragma unroll
        for (int q = 0; q < 4; ++q) {
            float x = (float)iq[q];
#pragma unroll
            for (int c = 0; c < 4; ++c) {
                float h = fmaxf(fmaf(x, (&w1v.x)[c], (&b1v.x)[c]), 0.0f);
                (&acc.x)[c] += h;
            }
        }
    }
    if (count & 63) {                            // masked tail iteration
        int base = nFull * 64 + g * 4;
        ushort4 idx4 = *(const ushort4*)&myidx[base];   // in-bounds (<=2048)
        const unsigned short* iq = (const unsigned short*)&idx4;
#pragma unroll
        for (int q = 0; q < 4; ++q) {
            float x    = (float)iq[q];           // garbage ok: finite, masked
            float mval = (base + q < count) ? 1.0f : 0.0f;
#pragma unroll
            for (int c = 0; c < 4; ++c) {
                float h = fmaxf(fmaf(x, (&w1v.x)[c], (&b1v.x)[c]), 0.0f);
                (&acc.x)[c] = fmaf(h, mval, (&acc.x)[c]);
            }
        }
    }

    // Reduce across the 16 index-groups: butterfly over strides 4,8,16,32.
#pragma unroll
    for (int off = 4; off < 64; off <<= 1) {
        acc.x += __shfl_xor(acc.x, off);
        acc.y += __shfl_xor(acc.y, off);
        acc.z += __shfl_xor(acc.z, off);
        acc.w += __shfl_xor(acc.w, off);
    }
    // Lane l holds s[4*(l&3)+c]; broadcast all 16 to every lane.
    float s[HID];
#pragma unroll
    for (int a = 0; a < 4; ++a) {
        s[4 * a + 0] = __shfl(acc.x, a);
        s[4 * a + 1] = __shfl(acc.y, a);
        s[4 * a + 2] = __shfl(acc.z, a);
        s[4 * a + 3] = __shfl(acc.w, a);
    }

    // ---- Epilogue: emb[d] = (sum_k s[k]*W2[k][d] + count*b2[d]) / max(count,1)
    // Lane l owns dims 2l, 2l+1. W2 (8KB) / b2 (512B) are L1-hot.
    const float cnt = (float)count;
    const float inv = 1.0f / fmaxf(cnt, 1.0f);
    const float2* __restrict__ W2v = (const float2*)W2;    // [16][64] float2
    float2 bv = ((const float2*)b2)[lane];
    float e0 = cnt * bv.x;
    float e1 = cnt * bv.y;
#pragma unroll
    for (int k = 0; k < HID; ++k) {
        float2 w = W2v[k * 64 + lane];
        e0 = fmaf(s[k], w.x, e0);
        e1 = fmaf(s[k], w.y, e1);
    }
    ((float2*)out)[row * 64 + lane] = make_float2(e0 * inv, e1 * inv);
}

extern "C" void kernel_launch(void* const* d_in, const int* in_sizes, int n_in,
                              void* d_out, int out_size, void* d_ws, size_t ws_size,
                              hipStream_t stream) {
    const float* M  = (const float*)d_in[0];   // [50000, 2000]
    const float* W1 = (const float*)d_in[1];   // [1, 16]
    const float* b1 = (const float*)d_in[2];   // [16]
    const float* W2 = (const float*)d_in[3];   // [16, 128]
    const float* b2 = (const float*)d_in[4];   // [128]
    float* out = (float*)d_out;                // [50000, 128]

    fused_gather_mean_kernel<<<NUM_LEARNERS / 4, 256, 0, stream>>>(
        M, W1, b1, W2, b2, out);
}